// Round 3
// baseline (67.360 us; speedup 1.0000x reference)
//
#include <hip/hip_runtime.h>
#include <math.h>
#include <stdint.h>

// Problem constants (from reference)
#define BATCH      1024
#define NB_REQ     8
#define INPUT_DIM  512
#define MAX_DEPTH  17
#define NB_CLASSES 100000
#define N_NODES    (NB_CLASSES - 1)
#define ITEMS      (BATCH * NB_REQ * MAX_DEPTH)   // 139264
#define CAP        16                              // max items per node slot list

// ---------------------------------------------------------------------------
// Node-inverted scheme: each unique W row is fetched from HBM exactly once.
//   Z    : zero per-node counters
//   BUILD: per (pair,depth) item, append item-id to its node's slot list
//   MAIN : one wave per node; load W row once, serve all its items
//   FIN  : per pair, product of its 17 factors
// ---------------------------------------------------------------------------

__global__ __launch_bounds__(256) void zero_kernel(uint32_t* __restrict__ cnt) {
    const int i = blockIdx.x * 256 + threadIdx.x;
    if (i < N_NODES) cnt[i] = 0u;
}

__global__ __launch_bounds__(256) void build_kernel(
    const int* __restrict__ targets,   // (BATCH, NB_REQ)
    const int* __restrict__ path,      // (NB_CLASSES, MAX_DEPTH)
    uint32_t*  __restrict__ cnt,       // (N_NODES,)
    uint32_t*  __restrict__ slots)     // (N_NODES, CAP)
{
    const int t = blockIdx.x * 256 + threadIdx.x;
    if (t >= ITEMS) return;
    const int pair = t / MAX_DEPTH;
    const int d    = t - pair * MAX_DEPTH;
    const int cls  = targets[pair];
    const int node = path[(size_t)cls * MAX_DEPTH + d];
    const uint32_t pos = atomicAdd(&cnt[node], 1u);
    if (pos < CAP) slots[(size_t)node * CAP + pos] = (uint32_t)t;
}

__global__ __launch_bounds__(256) void main_kernel(
    const float* __restrict__ x,        // (BATCH, INPUT_DIM)
    const int*   __restrict__ targets,  // (BATCH, NB_REQ)
    const float* __restrict__ W,        // (N_NODES, INPUT_DIM)
    const float* __restrict__ bias,     // (N_NODES,)
    const float* __restrict__ codes,    // (NB_CLASSES, MAX_DEPTH)
    const uint32_t* __restrict__ cnt,
    const uint32_t* __restrict__ slots,
    float*       __restrict__ fact)     // (ITEMS,) per-item branch factor
{
    const int wave = threadIdx.x >> 6;
    const int lane = threadIdx.x & 63;
    const int node = blockIdx.x * 4 + wave;
    if (node >= N_NODES) return;

    const uint32_t c0 = cnt[node];                 // wave-uniform broadcast
    const int c = __builtin_amdgcn_readfirstlane((int)(c0 > CAP ? CAP : c0));
    if (c == 0) return;

    // Load this node's W row ONCE: 8 floats / lane (2x float4, 2 KB total).
    const float4* wrow = reinterpret_cast<const float4*>(W + (size_t)node * INPUT_DIM);
    const float4 w0 = wrow[lane * 2 + 0];
    const float4 w1 = wrow[lane * 2 + 1];
    const float  bv = bias[node];

    for (int j = 0; j < c; ++j) {
        const int t    = __builtin_amdgcn_readfirstlane((int)slots[(size_t)node * CAP + j]);
        const int pair = t / MAX_DEPTH;
        const int d    = t - pair * MAX_DEPTH;
        const int bi   = pair >> 3;                // batch index

        // x row: 2 KB, L2-resident (x is 2 MB total).
        const float4* xrow = reinterpret_cast<const float4*>(x + (size_t)bi * INPUT_DIM);
        const float4 x0 = xrow[lane * 2 + 0];
        const float4 x1 = xrow[lane * 2 + 1];

        float acc = x0.x * w0.x + x0.y * w0.y + x0.z * w0.z + x0.w * w0.w
                  + x1.x * w1.x + x1.y * w1.y + x1.z * w1.z + x1.w * w1.w;

        #pragma unroll
        for (int off = 32; off >= 1; off >>= 1)
            acc += __shfl_xor(acc, off, 64);

        const int   cls = targets[pair];           // uniform
        const float h   = codes[(size_t)cls * MAX_DEPTH + d];
        const float p   = 1.0f / (1.0f + expf(-(acc + bv)));
        const float f   = h + p - 2.0f * h * p;    // p if h==0 else 1-p

        if (lane == 0) fact[t] = f;
    }
}

__global__ __launch_bounds__(256) void finalize_kernel(
    const float* __restrict__ fact,    // (ITEMS,)
    float*       __restrict__ out)     // (BATCH*NB_REQ,)
{
    const int pair = blockIdx.x * 256 + threadIdx.x;   // grid is exact: 8192
    float prod = 1.0f;
    #pragma unroll
    for (int d = 0; d < MAX_DEPTH; ++d)
        prod *= fact[(size_t)pair * MAX_DEPTH + d];
    out[pair] = prod;
}

extern "C" void kernel_launch(void* const* d_in, const int* in_sizes, int n_in,
                              void* d_out, int out_size, void* d_ws, size_t ws_size,
                              hipStream_t stream) {
    const float* x       = (const float*)d_in[0];  // input_vector (1024, 512)
    const int*   targets = (const int*)  d_in[1];  // target_classes (1024, 8)
    const float* W       = (const float*)d_in[2];  // W (99999, 512)
    const float* bias    = (const float*)d_in[3];  // b (99999,)
    const int*   path    = (const int*)  d_in[4];  // class_path_map (100000, 17)
    const float* codes   = (const float*)d_in[5];  // huffman_codes (100000, 17)
    float*       out     = (float*)d_out;          // (1024, 8)

    // Workspace layout (all 4B aligned; ~7.4 MB total, ws is much larger).
    uint32_t* cnt   = (uint32_t*)d_ws;                     // 99999
    uint32_t* slots = cnt + 100000;                        // 99999 * CAP
    float*    fact  = (float*)(slots + (size_t)100000 * CAP); // 139264

    zero_kernel    <<<(N_NODES + 255) / 256, 256, 0, stream>>>(cnt);
    build_kernel   <<<(ITEMS + 255) / 256,   256, 0, stream>>>(targets, path, cnt, slots);
    main_kernel    <<<(N_NODES + 3) / 4,     256, 0, stream>>>(x, targets, W, bias, codes,
                                                               cnt, slots, fact);
    finalize_kernel<<<BATCH * NB_REQ / 256,  256, 0, stream>>>(fact, out);
}